// Round 11
// baseline (246.434 us; speedup 1.0000x reference)
//
#include <hip/hip_runtime.h>
#include <hip/hip_bf16.h>
#include <math.h>

#define N_NODES 50000
#define IN_DIM 256
#define OUT_DIM 128
#define NUM_HEADS 2
#define N_EDGES 800000
#define F (OUT_DIM*NUM_HEADS)   /* 256 */
#define SCAN_B 1024
#define N_SB ((N_NODES + SCAN_B - 1) / SCAN_B)   /* 49 */
#define LDSP 264                 /* 256 + 8 pad: 132-word row stride = 4 mod 32 banks */
#define CAP 128                  /* per-wave LDS edge chunk in k_agg */
#define N_COPIES 8               /* XCD-private histogram copies */
#define NBLK_G2 ((N_NODES + 127) / 128)  /* 391 two-tile gemm blocks */
#define NBLK_H (N_EDGES / 256)   /* 3125 hist/scatter chunks, 1 edge/thread */
#define NBLK_FUSED (NBLK_G2 * 9) /* 3519: b%9==8 -> gemm (391), else hist (3128) */

typedef __bf16 bf16;
typedef __bf16 bf16x8 __attribute__((ext_vector_type(8)));
typedef float  f32x4  __attribute__((ext_vector_type(4)));
typedef unsigned short u16x8 __attribute__((ext_vector_type(8)));
typedef int    i32x4  __attribute__((ext_vector_type(4)));

// ---------------- K0: W -> Wt (bf16, transposed) + zero deg copies -------
__global__ void k_transpose(const float* __restrict__ W, bf16* __restrict__ Wt,
                            int* __restrict__ deg8) {
    int k = blockIdx.x;      // 0..IN_DIM-1
    int n = threadIdx.x;     // 0..F-1
    Wt[(size_t)n*IN_DIM + k] = (bf16)W[(size_t)k*F + n];
    int id = blockIdx.x * F + threadIdx.x;
    for (int i = id; i < N_COPIES * N_NODES; i += IN_DIM * F)
        deg8[i] = 0;
}

// ---------------- K1: FUSED gemm | hist (block-range split, 1:8) ---------
// b%9==8 -> two-tile gemm block q=b/9 (rows q*128..+128); else hist chunk
// hi=q*8+r (3128 slots, 3125 used). Round-11: each gemm block processes
// TWO 64-row A-tiles with B-frags loaded ONCE (halves gemm block count,
// amortizes the stage->sync->MFMA->epilogue latency chain over 2x work).
__global__ __launch_bounds__(256, 2) void k_gemm_hist(
                                              const float* __restrict__ X,
                                              const bf16* __restrict__ Wt,
                                              const float* __restrict__ Wb,
                                              const float* __restrict__ Av,
                                              const int* __restrict__ src,
                                              int* __restrict__ deg8,
                                              unsigned char* __restrict__ rank,
                                              int* __restrict__ xcdtab,
                                              bf16* __restrict__ Wh,
                                              float* __restrict__ s_arr,
                                              float* __restrict__ t_arr) {
    __shared__ bf16 As[64 * LDSP];
    __shared__ float sS[2][64], sT[2][64];
    int b = blockIdx.x;
    int q = b / 9, r9 = b % 9;
    int t = threadIdx.x;

    if (r9 != 8) {
        // ---------------- hist branch ----------------
        int hi = q * 8 + r9;
        if (hi >= NBLK_H) return;
        unsigned xcc;
        asm volatile("s_getreg_b32 %0, hwreg(HW_REG_XCC_ID, 0, 4)" : "=s"(xcc));
        xcc &= (N_COPIES - 1);
        if (t == 0) xcdtab[hi] = (int)xcc;
        int e = hi * 256 + t;                    // covers N_EDGES exactly
        int s = src[e];
        int rr = __hip_atomic_fetch_add(&deg8[(size_t)xcc * N_NODES + s], 1,
                                        __ATOMIC_RELAXED, __HIP_MEMORY_SCOPE_WORKGROUP);
        rank[e] = (unsigned char)rr;
        return;
    }

    // ---------------- gemm branch: two 64-row tiles, shared B-frags ------
    int wave = t >> 6, lane = t & 63;
    int quad = lane >> 4, l16 = lane & 15;
    int col0 = wave * 64;
    int h = wave >> 1;
    int rr = t >> 5;
    int cc = (t & 31) * 8;

    // B-frags + per-col constants loaded ONCE, reused for both tiles
    bf16x8 bfrag[4][8];
    #pragma unroll
    for (int ni = 0; ni < 4; ++ni)
        #pragma unroll
        for (int ks = 0; ks < 8; ++ks)
            bfrag[ni][ks] = *(const bf16x8*)(Wt + (size_t)(col0 + ni*16 + l16)*IN_DIM
                                                + ks*32 + quad*8);
    float bias_l[4], as_l[4], at_l[4];
    #pragma unroll
    for (int ni = 0; ni < 4; ++ni) {
        int c = col0 + ni*16 + l16;
        int d = c & (OUT_DIM - 1);
        bias_l[ni] = Wb[c];
        as_l[ni]   = Av[d];
        at_l[ni]   = Av[OUT_DIM + d];
    }

    for (int tt = 0; tt < 2; ++tt) {
        int row0 = q * 128 + tt * 64;

        // stage: issue 16 independent X loads, pack to LDS
        {
            f32x4 slo[8], shi[8];
            #pragma unroll
            for (int i = 0; i < 8; ++i) {
                int r = row0 + 8*i + rr;
                r = (r < N_NODES) ? r : (N_NODES - 1);
                const float* p = X + (size_t)r * IN_DIM + cc;
                slo[i] = *(const f32x4*)p;
                shi[i] = *(const f32x4*)(p + 4);
            }
            #pragma unroll
            for (int i = 0; i < 8; ++i) {
                bf16x8 pk;
                #pragma unroll
                for (int qq = 0; qq < 4; ++qq) {
                    pk[qq]   = (bf16)slo[i][qq];
                    pk[qq+4] = (bf16)shi[i][qq];
                }
                *(bf16x8*)(As + (8*i + rr) * LDSP + cc) = pk;
            }
        }
        if (t < 128) { sS[t >> 6][t & 63] = 0.f; sT[t >> 6][t & 63] = 0.f; }
        __syncthreads();

        // MFMA loop, LDS reads only (B in registers)
        f32x4 acc[4][4] = {};
        #pragma unroll
        for (int ks = 0; ks < 8; ++ks) {
            int kb = ks * 32;
            bf16x8 afrag[4];
            #pragma unroll
            for (int mi = 0; mi < 4; ++mi)
                afrag[mi] = *(const bf16x8*)(As + (mi*16 + l16)*LDSP + kb + quad*8);
            #pragma unroll
            for (int mi = 0; mi < 4; ++mi)
                #pragma unroll
                for (int ni = 0; ni < 4; ++ni)
                    acc[mi][ni] = __builtin_amdgcn_mfma_f32_16x16x32_bf16(
                                      afrag[mi], bfrag[ni][ks], acc[mi][ni], 0, 0, 0);
        }

        // s,t partials (C layout: col=lane&15, row=quad*4+reg)
        #pragma unroll
        for (int mi = 0; mi < 4; ++mi) {
            #pragma unroll
            for (int reg = 0; reg < 4; ++reg) {
                int rl = mi*16 + quad*4 + reg;
                float ps = 0.f, pt = 0.f;
                #pragma unroll
                for (int ni = 0; ni < 4; ++ni) {
                    float val = acc[mi][ni][reg] + bias_l[ni];
                    ps += val * as_l[ni];
                    pt += val * at_l[ni];
                }
                #pragma unroll
                for (int m = 8; m >= 1; m >>= 1) {
                    ps += __shfl_xor(ps, m);
                    pt += __shfl_xor(pt, m);
                }
                if ((lane & 15) == 0) {
                    atomicAdd(&sS[h][rl], ps);
                    atomicAdd(&sT[h][rl], pt);
                }
            }
        }

        // repack acc -> As (bias added) for coalesced Wh stores
        __syncthreads();
        #pragma unroll
        for (int mi = 0; mi < 4; ++mi)
            #pragma unroll
            for (int ni = 0; ni < 4; ++ni) {
                int ccc = col0 + ni*16 + l16;
                #pragma unroll
                for (int reg = 0; reg < 4; ++reg) {
                    int rl = mi*16 + quad*4 + reg;
                    As[rl*LDSP + ccc] = (bf16)(acc[mi][ni][reg] + bias_l[ni]);
                }
            }
        __syncthreads();

        // coalesced write-out: 8 rounds x (ds_read_b128 + store_dwordx4)
        #pragma unroll
        for (int i = 0; i < 8; ++i) {
            int idx = i * 2048 + t * 8;
            int row = idx >> 8;
            int ccw = idx & 255;
            bf16x8 v = *(const bf16x8*)(As + row*LDSP + ccw);
            int grow = row0 + row;
            if (grow < N_NODES)
                *(bf16x8*)(Wh + (size_t)grow*F + ccw) = v;
        }
        if (t < 128) {
            int hh = t >> 6, rl = t & 63;
            int n = row0 + rl;
            if (n < N_NODES) {
                s_arr[n*2 + hh] = sS[hh][rl];
                t_arr[n*2 + hh] = sT[hh][rl];
            }
        }
        if (tt == 0) __syncthreads();   // As/sS reuse hazard vs next tile
    }
}

// ---------------- K2: shuffle-based exclusive scan (folds 8 deg copies) --
__global__ __launch_bounds__(256) void k_scan_local(const int* __restrict__ deg8,
                                                    int* __restrict__ excl,
                                                    int* __restrict__ bsum,
                                                    unsigned short* __restrict__ prefix8) {
    __shared__ int wsum[4];
    int t = threadIdx.x;
    int wave = t >> 6, lane = t & 63;
    int base = blockIdx.x * SCAN_B + t * 4;        // 4 nodes per thread

    int tot[4] = {0, 0, 0, 0};
    u16x8 pf[4];
    {
        int run[4] = {0, 0, 0, 0};
        #pragma unroll
        for (int c = 0; c < N_COPIES; ++c) {
            i32x4 d = {0, 0, 0, 0};
            if (base + 3 < N_NODES)
                d = *(const i32x4*)(deg8 + (size_t)c * N_NODES + base);
            else if (base < N_NODES) {
                #pragma unroll
                for (int k = 0; k < 4; ++k)
                    d[k] = (base + k < N_NODES) ? deg8[(size_t)c * N_NODES + base + k] : 0;
            }
            #pragma unroll
            for (int k = 0; k < 4; ++k) {
                pf[k][c] = (unsigned short)run[k];
                run[k] += d[k];
            }
        }
        #pragma unroll
        for (int k = 0; k < 4; ++k) tot[k] = run[k];
    }
    int tsum = tot[0] + tot[1] + tot[2] + tot[3];

    int incl = tsum;
    #pragma unroll
    for (int off = 1; off < 64; off <<= 1) {
        int u = __shfl_up(incl, off);
        if (lane >= off) incl += u;
    }
    if (lane == 63) wsum[wave] = incl;
    __syncthreads();
    int w0 = wsum[0], w1 = wsum[1], w2 = wsum[2], w3 = wsum[3];
    int woff = (wave > 0 ? w0 : 0) + (wave > 1 ? w1 : 0) + (wave > 2 ? w2 : 0);
    int ebase = woff + incl - tsum;                // block-local exclusive

    if (base + 3 < N_NODES) {
        int run = ebase;
        #pragma unroll
        for (int k = 0; k < 4; ++k) {
            excl[base + k] = run;
            *(u16x8*)(prefix8 + (size_t)(base + k) * 8) = pf[k];
            run += tot[k];
        }
    } else {
        int run = ebase;
        #pragma unroll
        for (int k = 0; k < 4; ++k) {
            if (base + k < N_NODES) {
                excl[base + k] = run;
                *(u16x8*)(prefix8 + (size_t)(base + k) * 8) = pf[k];
            }
            run += tot[k];
        }
    }
    if (t == 0) bsum[blockIdx.x] = w0 + w1 + w2 + w3;
}

// ---------------- K3: ATOMIC-FREE scatter (inline block-sum scan) --------
__global__ __launch_bounds__(256) void k_scatter(const int* __restrict__ src,
                                                 const int* __restrict__ dst,
                                                 const unsigned char* __restrict__ rank,
                                                 const unsigned short* __restrict__ prefix8,
                                                 const int* __restrict__ excl,
                                                 const int* __restrict__ bsum,
                                                 const int* __restrict__ xcdtab,
                                                 int* __restrict__ sorted_dst) {
    __shared__ int sboff[64];
    int t = threadIdx.x;
    if (t < 64) {
        int orig = (t < N_SB) ? bsum[t] : 0;
        int v = orig;
        #pragma unroll
        for (int off = 1; off < 64; off <<= 1) {
            int u = __shfl_up(v, off);
            if (t >= off) v += u;
        }
        sboff[t] = v - orig;
    }
    __syncthreads();
    int e = blockIdx.x * 256 + t;                // grid covers N_EDGES exactly
    int c = xcdtab[blockIdx.x];                  // block-uniform scalar load
    int s = src[e];
    int pos = excl[s] + sboff[s >> 10] + (int)prefix8[(size_t)s * 8 + c] + (int)rank[e];
    sorted_dst[pos] = dst[e];
}

// ---------------- K4: fused softmax + gather+FMA aggregation -------------
// wave per node (round-9 form: k_agg is at its random-gather BW floor —
// 410MB of 64B lines / 65us = 6.3TB/s; MLP-deepening probe REGRESSED).
__global__ __launch_bounds__(256) void k_agg(const bf16* __restrict__ Wh,
                                             const float* __restrict__ s_arr,
                                             const float* __restrict__ t_arr,
                                             const int* __restrict__ excl,
                                             const int* __restrict__ bsum,
                                             const int* __restrict__ sdst,
                                             float* __restrict__ out) {
    __shared__ float sp0[4][CAP];
    __shared__ float sp1[4][CAP];
    __shared__ int   sd[4][CAP];
    __shared__ int   sboff[64];
    int t = threadIdx.x;
    if (t < 64) {
        int orig = (t < N_SB) ? bsum[t] : 0;
        int v = orig;
        #pragma unroll
        for (int off = 1; off < 64; off <<= 1) {
            int u = __shfl_up(v, off);
            if (t >= off) v += u;
        }
        sboff[t] = v - orig;
    }
    __syncthreads();

    int wave = t >> 6, lane = t & 63;
    int n = blockIdx.x * 4 + wave;
    int sub = lane >> 5, cl = lane & 31;
    int c = cl * 8, h = cl >> 4;
    int beg = excl[n] + sboff[n >> 10];
    int end = (n + 1 < N_NODES) ? excl[n + 1] + sboff[(n + 1) >> 10] : N_EDGES;
    if (beg == end) {       // isolated node: h' = Wh
        if (sub == 0) {
            bf16x8 wh = *(const bf16x8*)(Wh + (size_t)n*F + c);
            f32x4 o0, o1;
            #pragma unroll
            for (int i = 0; i < 4; ++i) { o0[i] = (float)wh[i]; o1[i] = (float)wh[4+i]; }
            *(f32x4*)(out + (size_t)n*F + c)     = o0;
            *(f32x4*)(out + (size_t)n*F + c + 4) = o1;
        }
        return;
    }
    float2 sv = ((const float2*)s_arr)[n];
    float sum0 = 0.f, sum1 = 0.f;
    float a[8] = {0,0,0,0,0,0,0,0};
    float bacc[8] = {0,0,0,0,0,0,0,0};
    const float* sph = h ? sp1[wave] : sp0[wave];

    for (int c0 = beg; c0 < end; c0 += CAP) {
        int cnt = min(CAP, end - c0);
        // Phase A: fill p/d chunk (wave-local)
        for (int j = lane; j < cnt; j += 64) {
            int d = sdst[c0 + j];
            float2 tv = ((const float2*)t_arr)[d];
            float e0 = sv.x + tv.x; e0 = (e0 >= 0.f) ? e0 : 0.2f * e0;
            float e1 = sv.y + tv.y; e1 = (e1 >= 0.f) ? e1 : 0.2f * e1;
            float p0 = __expf(e0), p1 = __expf(e1);
            sp0[wave][j] = p0;
            sp1[wave][j] = p1;
            sd[wave][j]  = d;
            sum0 += p0;
            sum1 += p1;
        }
        // Phase B: gather + FMA (8 edges/iter, 4 per sub-slot)
        int j = 0;
        for (; j + 8 <= cnt; j += 8) {
            int j0 = j + sub, j1 = j + 2 + sub, j2 = j + 4 + sub, j3 = j + 6 + sub;
            int d0 = sd[wave][j0], d1 = sd[wave][j1];
            int d2 = sd[wave][j2], d3 = sd[wave][j3];
            float p0 = sph[j0], p1 = sph[j1], p2 = sph[j2], p3 = sph[j3];
            bf16x8 w0 = *(const bf16x8*)(Wh + (size_t)d0*F + c);
            bf16x8 w1 = *(const bf16x8*)(Wh + (size_t)d1*F + c);
            bf16x8 w2 = *(const bf16x8*)(Wh + (size_t)d2*F + c);
            bf16x8 w3 = *(const bf16x8*)(Wh + (size_t)d3*F + c);
            #pragma unroll
            for (int i = 0; i < 8; ++i) {
                a[i]    += p0 * (float)w0[i];
                bacc[i] += p1 * (float)w1[i];
                a[i]    += p2 * (float)w2[i];
                bacc[i] += p3 * (float)w3[i];
            }
        }
        for (; j < cnt; j += 2) {
            int jj = j + sub;
            int jc = (jj < cnt) ? jj : 0;
            float p = (jj < cnt) ? sph[jc] : 0.f;
            int d = sd[wave][jc];
            bf16x8 w = *(const bf16x8*)(Wh + (size_t)d*F + c);
            #pragma unroll
            for (int i = 0; i < 8; ++i) a[i] += p * (float)w[i];
        }
    }
    #pragma unroll
    for (int m = 32; m >= 1; m >>= 1) {
        sum0 += __shfl_xor(sum0, m);
        sum1 += __shfl_xor(sum1, m);
    }
    float inv = 1.f / (h ? sum1 : sum0);
    #pragma unroll
    for (int i = 0; i < 8; ++i) {
        a[i] += bacc[i];
        a[i] += __shfl_xor(a[i], 32);      // merge odd-slot partial
    }
    if (sub == 0) {
        f32x4 o0, o1;
        #pragma unroll
        for (int i = 0; i < 4; ++i) { o0[i] = a[i] * inv; o1[i] = a[4+i] * inv; }
        *(f32x4*)(out + (size_t)n*F + c)     = o0;
        *(f32x4*)(out + (size_t)n*F + c + 4) = o1;
    }
}

// ---------------- launch ----------------
extern "C" void kernel_launch(void* const* d_in, const int* in_sizes, int n_in,
                              void* d_out, int out_size, void* d_ws, size_t ws_size,
                              hipStream_t stream) {
    const float* x  = (const float*)d_in[0];
    const int*   ei = (const int*)d_in[1];
    const float* Ww = (const float*)d_in[2];
    const float* Wb = (const float*)d_in[3];
    const float* a  = (const float*)d_in[4];
    float* out = (float*)d_out;
    const int* src = ei;              // edge_index[0]
    const int* dst = ei + N_EDGES;    // edge_index[1]

    // workspace layout (~32 MB), 16B-aligned slices
    char* ws = (char*)d_ws;
    bf16*  Wh        = (bf16*)ws;   ws += (size_t)N_NODES * F * 2;       // 25.6 MB
    bf16*  Wt        = (bf16*)ws;   ws += (size_t)IN_DIM * F * 2;        // 128 KB
    float* s_arr     = (float*)ws;  ws += (size_t)N_NODES * 2 * 4;
    float* t_arr     = (float*)ws;  ws += (size_t)N_NODES * 2 * 4;
    int*   excl      = (int*)ws;    ws += (size_t)N_NODES * 4;
    int*   bsum      = (int*)ws;    ws += 64 * 4;
    unsigned short* prefix8 = (unsigned short*)ws; ws += (size_t)N_NODES * 8 * 2; // 800 KB
    unsigned char*  rank    = (unsigned char*)ws;  ws += (size_t)N_EDGES + 16;    // 800 KB
    int*   xcdtab    = (int*)ws;    ws += (size_t)NBLK_H * 4 + 12;       // pad to 16B
    int*   sdst      = (int*)ws;    ws += (size_t)N_EDGES * 4;           // 3.2 MB

    // deg8 (8 x N_NODES = 1.6 MB) ALIASES sdst: deg copies are consumed by
    // k_scan_local (disp 3) strictly before k_scatter writes sdst (disp 4).
    int* deg8 = sdst;

    k_transpose<<<IN_DIM, F, 0, stream>>>(Ww, Wt, deg8);
    k_gemm_hist<<<NBLK_FUSED, 256, 0, stream>>>(x, Wt, Wb, a, src, deg8, rank,
                                                xcdtab, Wh, s_arr, t_arr);
    k_scan_local<<<N_SB, 256, 0, stream>>>(deg8, excl, bsum, prefix8);
    k_scatter<<<NBLK_H, 256, 0, stream>>>(src, dst, rank, prefix8, excl, bsum,
                                          xcdtab, sdst);
    k_agg<<<N_NODES / 4, 256, 0, stream>>>(Wh, s_arr, t_arr, excl, bsum, sdst, out);
}

// Round 12
// 227.284 us; speedup vs baseline: 1.0843x; 1.0843x over previous
//
#include <hip/hip_runtime.h>
#include <hip/hip_bf16.h>
#include <math.h>

#define N_NODES 50000
#define IN_DIM 256
#define OUT_DIM 128
#define NUM_HEADS 2
#define N_EDGES 800000
#define F (OUT_DIM*NUM_HEADS)   /* 256 */
#define SCAN_B 1024
#define N_SB ((N_NODES + SCAN_B - 1) / SCAN_B)   /* 49 */
#define LDSP 264                 /* 256 + 8 pad: 132-word row stride = 4 mod 32 banks */
#define CAP 128                  /* per-wave LDS edge chunk in k_agg */
#define N_COPIES 8               /* XCD-private histogram copies */
#define NBLK_H (N_EDGES / 256)   /* 3125 hist/scatter chunks, 1 edge/thread */
#define NBLK_FUSED 3910          /* 782*5: b%5==4 -> gemm (782), else hist (3128) */

typedef __bf16 bf16;
typedef __bf16 bf16x8 __attribute__((ext_vector_type(8)));
typedef float  f32x4  __attribute__((ext_vector_type(4)));
typedef int    i32x4  __attribute__((ext_vector_type(4)));

// ---------------- K0: W -> Wt (bf16, transposed) + zero deg copies -------
__global__ void k_transpose(const float* __restrict__ W, bf16* __restrict__ Wt,
                            int* __restrict__ deg8) {
    int k = blockIdx.x;      // 0..IN_DIM-1
    int n = threadIdx.x;     // 0..F-1
    Wt[(size_t)n*IN_DIM + k] = (bf16)W[(size_t)k*F + n];
    int id = blockIdx.x * F + threadIdx.x;
    for (int i = id; i < N_COPIES * N_NODES; i += IN_DIM * F)
        deg8[i] = 0;
}

// ---------------- K1: FUSED gemm | hist (block-range split, 1:4) ---------
// b%5==4 -> single-tile gemm block q=b/5 (782 tiles); else hist chunk
// hi=q*4+r (3128 slots, 3125 used). Round-12: reverted to the single-tile
// form (two-tile variant pushed VGPR to 128, occupancy to 14%, -17us).
__global__ __launch_bounds__(256, 2) void k_gemm_hist(
                                              const float* __restrict__ X,
                                              const bf16* __restrict__ Wt,
                                              const float* __restrict__ Wb,
                                              const float* __restrict__ Av,
                                              const int* __restrict__ src,
                                              int* __restrict__ deg8,
                                              unsigned char* __restrict__ rank,
                                              int* __restrict__ xcdtab,
                                              bf16* __restrict__ Wh,
                                              float* __restrict__ s_arr,
                                              float* __restrict__ t_arr) {
    __shared__ bf16 As[64 * LDSP];
    __shared__ float sS[2][64], sT[2][64];
    int b = blockIdx.x;
    int q = b / 5, r5 = b % 5;
    int t = threadIdx.x;

    if (r5 != 4) {
        // ---------------- hist branch ----------------
        int hi = q * 4 + r5;
        if (hi >= NBLK_H) return;
        unsigned xcc;
        asm volatile("s_getreg_b32 %0, hwreg(HW_REG_XCC_ID, 0, 4)" : "=s"(xcc));
        xcc &= (N_COPIES - 1);
        if (t == 0) xcdtab[hi] = (int)xcc;
        int e = hi * 256 + t;                    // covers N_EDGES exactly
        int s = src[e];
        int rr = __hip_atomic_fetch_add(&deg8[(size_t)xcc * N_NODES + s], 1,
                                        __ATOMIC_RELAXED, __HIP_MEMORY_SCOPE_WORKGROUP);
        rank[e] = (unsigned char)rr;
        return;
    }

    // ---------------- gemm branch (tile index q) ----------
    int wave = t >> 6, lane = t & 63;
    int quad = lane >> 4, l16 = lane & 15;
    int row0 = q * 64;
    int col0 = wave * 64;
    int h = wave >> 1;

    // phase 1a: issue X staging loads (16 dwordx4 per thread, independent)
    int rr = t >> 5;
    int cc = (t & 31) * 8;
    f32x4 slo[8], shi[8];
    #pragma unroll
    for (int i = 0; i < 8; ++i) {
        int r = row0 + 8*i + rr;
        r = (r < N_NODES) ? r : (N_NODES - 1);
        const float* p = X + (size_t)r * IN_DIM + cc;
        slo[i] = *(const f32x4*)p;
        shi[i] = *(const f32x4*)(p + 4);
    }

    // phase 1b: issue all 32 B-frag gathers (independent, live across barrier)
    bf16x8 bfrag[4][8];
    #pragma unroll
    for (int ni = 0; ni < 4; ++ni)
        #pragma unroll
        for (int ks = 0; ks < 8; ++ks)
            bfrag[ni][ks] = *(const bf16x8*)(Wt + (size_t)(col0 + ni*16 + l16)*IN_DIM
                                                + ks*32 + quad*8);

    // phase 1c: convert + write staging tile to LDS (waits only on X loads)
    #pragma unroll
    for (int i = 0; i < 8; ++i) {
        bf16x8 pk;
        #pragma unroll
        for (int qq = 0; qq < 4; ++qq) {
            pk[qq]   = (bf16)slo[i][qq];
            pk[qq+4] = (bf16)shi[i][qq];
        }
        *(bf16x8*)(As + (8*i + rr) * LDSP + cc) = pk;
    }
    if (t < 128) { sS[t >> 6][t & 63] = 0.f; sT[t >> 6][t & 63] = 0.f; }
    __syncthreads();

    // phase 2: MFMA loop, LDS reads only (B already in registers)
    f32x4 acc[4][4] = {};
    #pragma unroll
    for (int ks = 0; ks < 8; ++ks) {
        int kb = ks * 32;
        bf16x8 afrag[4];
        #pragma unroll
        for (int mi = 0; mi < 4; ++mi)
            afrag[mi] = *(const bf16x8*)(As + (mi*16 + l16)*LDSP + kb + quad*8);

        #pragma unroll
        for (int mi = 0; mi < 4; ++mi)
            #pragma unroll
            for (int ni = 0; ni < 4; ++ni)
                acc[mi][ni] = __builtin_amdgcn_mfma_f32_16x16x32_bf16(
                                  afrag[mi], bfrag[ni][ks], acc[mi][ni], 0, 0, 0);
    }

    float bias_l[4], as_l[4], at_l[4];
    #pragma unroll
    for (int ni = 0; ni < 4; ++ni) {
        int c = col0 + ni*16 + l16;
        int d = c & (OUT_DIM - 1);
        bias_l[ni] = Wb[c];
        as_l[ni]   = Av[d];
        at_l[ni]   = Av[OUT_DIM + d];
    }

    // s,t partials from accumulators (C layout: col=lane&15, row=quad*4+reg)
    #pragma unroll
    for (int mi = 0; mi < 4; ++mi) {
        #pragma unroll
        for (int reg = 0; reg < 4; ++reg) {
            int rl = mi*16 + quad*4 + reg;
            float ps = 0.f, pt = 0.f;
            #pragma unroll
            for (int ni = 0; ni < 4; ++ni) {
                float val = acc[mi][ni][reg] + bias_l[ni];
                ps += val * as_l[ni];
                pt += val * at_l[ni];
            }
            #pragma unroll
            for (int m = 8; m >= 1; m >>= 1) {
                ps += __shfl_xor(ps, m);
                pt += __shfl_xor(pt, m);
            }
            if ((lane & 15) == 0) {
                atomicAdd(&sS[h][rl], ps);
                atomicAdd(&sT[h][rl], pt);
            }
        }
    }

    // repack acc -> As (bias added) for coalesced Wh stores
    __syncthreads();          // all waves done with As compute reads
    #pragma unroll
    for (int mi = 0; mi < 4; ++mi)
        #pragma unroll
        for (int ni = 0; ni < 4; ++ni) {
            int ccc = col0 + ni*16 + l16;
            #pragma unroll
            for (int reg = 0; reg < 4; ++reg) {
                int rl = mi*16 + quad*4 + reg;
                As[rl*LDSP + ccc] = (bf16)(acc[mi][ni][reg] + bias_l[ni]);
            }
        }
    __syncthreads();

    // coalesced write-out: 8 rounds x (ds_read_b128 + global_store_dwordx4)
    #pragma unroll
    for (int i = 0; i < 8; ++i) {
        int idx = i * 2048 + t * 8;     // 2048 elems (=8 rows) per round
        int row = idx >> 8;
        int ccw = idx & 255;
        bf16x8 v = *(const bf16x8*)(As + row*LDSP + ccw);
        int grow = row0 + row;
        if (grow < N_NODES)
            *(bf16x8*)(Wh + (size_t)grow*F + ccw) = v;
    }

    if (t < 128) {
        int hh = t >> 6, rl = t & 63;
        int n = row0 + rl;
        if (n < N_NODES) {
            s_arr[n*2 + hh] = sS[hh][rl];
            t_arr[n*2 + hh] = sT[hh][rl];
        }
    }
}

// ---------------- K2: shuffle-based exclusive scan (folds 8 deg copies) --
// Round-12: also emits base8[c][s] = excl_local[s] + prefix8[s][c] so
// k_scatter needs ONE random gather per edge instead of two.
__global__ __launch_bounds__(256) void k_scan_local(const int* __restrict__ deg8,
                                                    int* __restrict__ excl,
                                                    int* __restrict__ bsum,
                                                    int* __restrict__ base8) {
    __shared__ int wsum[4];
    int t = threadIdx.x;
    int wave = t >> 6, lane = t & 63;
    int base = blockIdx.x * SCAN_B + t * 4;        // 4 nodes per thread

    int tot[4] = {0, 0, 0, 0};
    unsigned short pf[4][N_COPIES];
    {
        int run[4] = {0, 0, 0, 0};
        #pragma unroll
        for (int c = 0; c < N_COPIES; ++c) {
            i32x4 d = {0, 0, 0, 0};
            if (base + 3 < N_NODES)
                d = *(const i32x4*)(deg8 + (size_t)c * N_NODES + base);
            else if (base < N_NODES) {
                #pragma unroll
                for (int k = 0; k < 4; ++k)
                    d[k] = (base + k < N_NODES) ? deg8[(size_t)c * N_NODES + base + k] : 0;
            }
            #pragma unroll
            for (int k = 0; k < 4; ++k) {
                pf[k][c] = (unsigned short)run[k];
                run[k] += d[k];
            }
        }
        #pragma unroll
        for (int k = 0; k < 4; ++k) tot[k] = run[k];
    }
    int tsum = tot[0] + tot[1] + tot[2] + tot[3];

    // 64-lane inclusive shuffle scan of tsum
    int incl = tsum;
    #pragma unroll
    for (int off = 1; off < 64; off <<= 1) {
        int u = __shfl_up(incl, off);
        if (lane >= off) incl += u;
    }
    if (lane == 63) wsum[wave] = incl;
    __syncthreads();
    int w0 = wsum[0], w1 = wsum[1], w2 = wsum[2], w3 = wsum[3];
    int woff = (wave > 0 ? w0 : 0) + (wave > 1 ? w1 : 0) + (wave > 2 ? w2 : 0);
    int ebase = woff + incl - tsum;                // block-local exclusive

    int r0 = ebase;
    int r1 = r0 + tot[0];
    int r2 = r1 + tot[1];
    int r3 = r2 + tot[2];

    if (base + 3 < N_NODES) {
        i32x4 ex = {r0, r1, r2, r3};
        *(i32x4*)(excl + base) = ex;
        #pragma unroll
        for (int c = 0; c < N_COPIES; ++c) {
            i32x4 v = {r0 + (int)pf[0][c], r1 + (int)pf[1][c],
                       r2 + (int)pf[2][c], r3 + (int)pf[3][c]};
            *(i32x4*)(base8 + (size_t)c * N_NODES + base) = v;
        }
    } else if (base < N_NODES) {
        int rr[4] = {r0, r1, r2, r3};
        #pragma unroll
        for (int k = 0; k < 4; ++k) {
            if (base + k < N_NODES) {
                excl[base + k] = rr[k];
                #pragma unroll
                for (int c = 0; c < N_COPIES; ++c)
                    base8[(size_t)c * N_NODES + base + k] = rr[k] + (int)pf[k][c];
            }
        }
    }
    if (t == 0) bsum[blockIdx.x] = w0 + w1 + w2 + w3;
}

// ---------------- K3: ATOMIC-FREE scatter (single-gather addressing) -----
// pos = base8[c][s] + sboff[s>>10] + rank[e]; c = XCD that histogrammed e.
__global__ __launch_bounds__(256) void k_scatter(const int* __restrict__ src,
                                                 const int* __restrict__ dst,
                                                 const unsigned char* __restrict__ rank,
                                                 const int* __restrict__ base8,
                                                 const int* __restrict__ bsum,
                                                 const int* __restrict__ xcdtab,
                                                 int* __restrict__ sorted_dst) {
    __shared__ int sboff[64];
    int t = threadIdx.x;
    if (t < 64) {
        int orig = (t < N_SB) ? bsum[t] : 0;
        int v = orig;
        #pragma unroll
        for (int off = 1; off < 64; off <<= 1) {
            int u = __shfl_up(v, off);
            if (t >= off) v += u;
        }
        sboff[t] = v - orig;
    }
    __syncthreads();
    int e = blockIdx.x * 256 + t;                // grid covers N_EDGES exactly
    int c = xcdtab[blockIdx.x];                  // block-uniform scalar load
    int s = src[e];
    int pos = base8[(size_t)c * N_NODES + s] + sboff[s >> 10] + (int)rank[e];
    sorted_dst[pos] = dst[e];
}

// ---------------- K4: fused softmax + gather+FMA aggregation -------------
// wave per node (round-9 form: k_agg is at its random-gather BW floor —
// 410MB of lines / 65us = 6.3TB/s delivered; deepening MLP regressed).
__global__ __launch_bounds__(256) void k_agg(const bf16* __restrict__ Wh,
                                             const float* __restrict__ s_arr,
                                             const float* __restrict__ t_arr,
                                             const int* __restrict__ excl,
                                             const int* __restrict__ bsum,
                                             const int* __restrict__ sdst,
                                             float* __restrict__ out) {
    __shared__ float sp0[4][CAP];
    __shared__ float sp1[4][CAP];
    __shared__ int   sd[4][CAP];
    __shared__ int   sboff[64];
    int t = threadIdx.x;
    if (t < 64) {
        int orig = (t < N_SB) ? bsum[t] : 0;
        int v = orig;
        #pragma unroll
        for (int off = 1; off < 64; off <<= 1) {
            int u = __shfl_up(v, off);
            if (t >= off) v += u;
        }
        sboff[t] = v - orig;
    }
    __syncthreads();

    int wave = t >> 6, lane = t & 63;
    int n = blockIdx.x * 4 + wave;
    int sub = lane >> 5, cl = lane & 31;
    int c = cl * 8, h = cl >> 4;
    int beg = excl[n] + sboff[n >> 10];
    int end = (n + 1 < N_NODES) ? excl[n + 1] + sboff[(n + 1) >> 10] : N_EDGES;
    if (beg == end) {       // isolated node: h' = Wh
        if (sub == 0) {
            bf16x8 wh = *(const bf16x8*)(Wh + (size_t)n*F + c);
            f32x4 o0, o1;
            #pragma unroll
            for (int i = 0; i < 4; ++i) { o0[i] = (float)wh[i]; o1[i] = (float)wh[4+i]; }
            *(f32x4*)(out + (size_t)n*F + c)     = o0;
            *(f32x4*)(out + (size_t)n*F + c + 4) = o1;
        }
        return;
    }
    float2 sv = ((const float2*)s_arr)[n];
    float sum0 = 0.f, sum1 = 0.f;
    float a[8] = {0,0,0,0,0,0,0,0};
    float bacc[8] = {0,0,0,0,0,0,0,0};
    const float* sph = h ? sp1[wave] : sp0[wave];

    for (int c0 = beg; c0 < end; c0 += CAP) {
        int cnt = min(CAP, end - c0);
        // Phase A: fill p/d chunk (wave-local)
        for (int j = lane; j < cnt; j += 64) {
            int d = sdst[c0 + j];
            float2 tv = ((const float2*)t_arr)[d];
            float e0 = sv.x + tv.x; e0 = (e0 >= 0.f) ? e0 : 0.2f * e0;
            float e1 = sv.y + tv.y; e1 = (e1 >= 0.f) ? e1 : 0.2f * e1;
            float p0 = __expf(e0), p1 = __expf(e1);
            sp0[wave][j] = p0;
            sp1[wave][j] = p1;
            sd[wave][j]  = d;
            sum0 += p0;
            sum1 += p1;
        }
        // Phase B: gather + FMA (8 edges/iter, 4 per sub-slot)
        int j = 0;
        for (; j + 8 <= cnt; j += 8) {
            int j0 = j + sub, j1 = j + 2 + sub, j2 = j + 4 + sub, j3 = j + 6 + sub;
            int d0 = sd[wave][j0], d1 = sd[wave][j1];
            int d2 = sd[wave][j2], d3 = sd[wave][j3];
            float p0 = sph[j0], p1 = sph[j1], p2 = sph[j2], p3 = sph[j3];
            bf16x8 w0 = *(const bf16x8*)(Wh + (size_t)d0*F + c);
            bf16x8 w1 = *(const bf16x8*)(Wh + (size_t)d1*F + c);
            bf16x8 w2 = *(const bf16x8*)(Wh + (size_t)d2*F + c);
            bf16x8 w3 = *(const bf16x8*)(Wh + (size_t)d3*F + c);
            #pragma unroll
            for (int i = 0; i < 8; ++i) {
                a[i]    += p0 * (float)w0[i];
                bacc[i] += p1 * (float)w1[i];
                a[i]    += p2 * (float)w2[i];
                bacc[i] += p3 * (float)w3[i];
            }
        }
        for (; j < cnt; j += 2) {
            int jj = j + sub;
            int jc = (jj < cnt) ? jj : 0;
            float p = (jj < cnt) ? sph[jc] : 0.f;
            int d = sd[wave][jc];
            bf16x8 w = *(const bf16x8*)(Wh + (size_t)d*F + c);
            #pragma unroll
            for (int i = 0; i < 8; ++i) a[i] += p * (float)w[i];
        }
    }
    #pragma unroll
    for (int m = 32; m >= 1; m >>= 1) {
        sum0 += __shfl_xor(sum0, m);
        sum1 += __shfl_xor(sum1, m);
    }
    float inv = 1.f / (h ? sum1 : sum0);
    #pragma unroll
    for (int i = 0; i < 8; ++i) {
        a[i] += bacc[i];
        a[i] += __shfl_xor(a[i], 32);      // merge odd-slot partial
    }
    if (sub == 0) {
        f32x4 o0, o1;
        #pragma unroll
        for (int i = 0; i < 4; ++i) { o0[i] = a[i] * inv; o1[i] = a[4+i] * inv; }
        *(f32x4*)(out + (size_t)n*F + c)     = o0;
        *(f32x4*)(out + (size_t)n*F + c + 4) = o1;
    }
}

// ---------------- launch ----------------
extern "C" void kernel_launch(void* const* d_in, const int* in_sizes, int n_in,
                              void* d_out, int out_size, void* d_ws, size_t ws_size,
                              hipStream_t stream) {
    const float* x  = (const float*)d_in[0];
    const int*   ei = (const int*)d_in[1];
    const float* Ww = (const float*)d_in[2];
    const float* Wb = (const float*)d_in[3];
    const float* a  = (const float*)d_in[4];
    float* out = (float*)d_out;
    const int* src = ei;              // edge_index[0]
    const int* dst = ei + N_EDGES;    // edge_index[1]

    // workspace layout (~33 MB), 16B-aligned slices
    char* ws = (char*)d_ws;
    bf16*  Wh        = (bf16*)ws;   ws += (size_t)N_NODES * F * 2;       // 25.6 MB
    bf16*  Wt        = (bf16*)ws;   ws += (size_t)IN_DIM * F * 2;        // 128 KB
    float* s_arr     = (float*)ws;  ws += (size_t)N_NODES * 2 * 4;
    float* t_arr     = (float*)ws;  ws += (size_t)N_NODES * 2 * 4;
    int*   excl      = (int*)ws;    ws += (size_t)N_NODES * 4;
    int*   bsum      = (int*)ws;    ws += 64 * 4;
    int*   base8     = (int*)ws;    ws += (size_t)N_COPIES * N_NODES * 4; // 1.6 MB
    unsigned char* rank = (unsigned char*)ws; ws += (size_t)N_EDGES + 16; // 800 KB
    int*   xcdtab    = (int*)ws;    ws += (size_t)NBLK_H * 4 + 12;       // pad to 16B
    int*   sdst      = (int*)ws;    ws += (size_t)N_EDGES * 4;           // 3.2 MB

    // deg8 (8 x N_NODES = 1.6 MB) ALIASES sdst: deg copies are consumed by
    // k_scan_local (disp 3) strictly before k_scatter writes sdst (disp 4).
    int* deg8 = sdst;

    k_transpose<<<IN_DIM, F, 0, stream>>>(Ww, Wt, deg8);
    k_gemm_hist<<<NBLK_FUSED, 256, 0, stream>>>(x, Wt, Wb, a, src, deg8, rank,
                                                xcdtab, Wh, s_arr, t_arr);
    k_scan_local<<<N_SB, 256, 0, stream>>>(deg8, excl, bsum, base8);
    k_scatter<<<NBLK_H, 256, 0, stream>>>(src, dst, rank, base8, bsum,
                                          xcdtab, sdst);
    k_agg<<<N_NODES / 4, 256, 0, stream>>>(Wh, s_arr, t_arr, excl, bsum, sdst, out);
}